// Round 5
// baseline (149.768 us; speedup 1.0000x reference)
//
#include <hip/hip_runtime.h>

#define T 256
#define H 512
#define EPSF 1e-5f

__device__ __forceinline__ float block_sum(float v, float* s4) {
    for (int o = 32; o; o >>= 1) v += __shfl_xor(v, o);
    int w = threadIdx.x >> 6;
    __syncthreads();
    if ((threadIdx.x & 63) == 0) s4[w] = v;
    __syncthreads();
    return s4[0] + s4[1] + s4[2] + s4[3];
}

__device__ __forceinline__ float block_max(float v, float* s4) {
    for (int o = 32; o; o >>= 1) v = fmaxf(v, __shfl_xor(v, o));
    int w = threadIdx.x >> 6;
    __syncthreads();
    if ((threadIdx.x & 63) == 0) s4[w] = v;
    __syncthreads();
    return fmaxf(fmaxf(s4[0], s4[1]), fmaxf(s4[2], s4[3]));
}

// bid 0,1: S scan. bid 2..513: Z=relu(h@U+a), HZ=h.*Z, c=rowsum(h).
// GEMM tile 2t x 128q, split-K: wave-group g=tid>>6, r=g&1 (row), kc=g>>1 (k-half).
__global__ __launch_bounds__(256) void k1(
        const float* __restrict__ h, const float* __restrict__ U,
        const float* __restrict__ a, float* __restrict__ Z,
        float* __restrict__ HZ, float* __restrict__ c, float* __restrict__ S) {
    int bid = blockIdx.x, tid = threadIdx.x;
    if (bid < 2) {
        int q = bid * 256 + tid;
        float acc = 0.f;
        for (int t0 = 0; t0 < T; t0 += 8) {
            float v[8];
            #pragma unroll
            for (int u = 0; u < 8; ++u) v[u] = h[(t0 + u) * H + q];
            #pragma unroll
            for (int u = 0; u < 8; ++u) { acc += v[u]; S[(t0 + u) * H + q] = acc; }
        }
        return;
    }
    int b = bid - 2;
    int t0 = (b >> 2) * 2;          // 0..254
    int qo = (b & 3) * 128;
    __shared__ __align__(16) float At[2 * H];
    __shared__ float part[256];
    ((float4*)At)[tid] = ((const float4*)(h + t0 * H))[tid];
    __syncthreads();

    if ((b & 3) == 0 && tid < 128) {          // c for rows t0, t0+1 (waves 0,1)
        int w = tid >> 6, lane = tid & 63;
        float s = 0.f;
        #pragma unroll
        for (int j = 0; j < 8; ++j) s += At[w * H + lane + j * 64];
        for (int o = 32; o; o >>= 1) s += __shfl_xor(s, o);
        if (lane == 0) c[t0 + w] = s;
    }

    int c2 = tid & 63, g = tid >> 6, r = g & 1, kc = g >> 1;
    int qc = (qo >> 1) + c2;
    const float2* U2 = (const float2*)U;
    float accx = 0.f, accy = 0.f;
    int kbeg = kc * 256;
    for (int k0 = kbeg; k0 < kbeg + 256; k0 += 8) {
        float2 bv[8];
        #pragma unroll
        for (int u = 0; u < 8; ++u) bv[u] = U2[(k0 + u) * 256 + qc];
        float4 f0 = *(const float4*)&At[r * H + k0];
        float4 f1 = *(const float4*)&At[r * H + k0 + 4];
        float av[8] = {f0.x, f0.y, f0.z, f0.w, f1.x, f1.y, f1.z, f1.w};
        #pragma unroll
        for (int u = 0; u < 8; ++u) { accx += av[u] * bv[u].x; accy += av[u] * bv[u].y; }
    }
    if (kc == 1) { part[(r * 64 + c2) * 2] = accx; part[(r * 64 + c2) * 2 + 1] = accy; }
    __syncthreads();
    if (kc == 0) {
        accx += part[(r * 64 + c2) * 2];
        accy += part[(r * 64 + c2) * 2 + 1];
        float2 ab = ((const float2*)a)[qc];
        float zx = fmaxf(accx + ab.x, 0.f), zy = fmaxf(accy + ab.y, 0.f);
        float hx = At[r * H + 2 * qc], hy = At[r * H + 2 * qc + 1];
        int t = t0 + r;
        ((float2*)Z)[t * 256 + qc]  = make_float2(zx, zy);
        ((float2*)HZ)[t * 256 + qc] = make_float2(hx * zx, hy * zy);
    }
}

// bid 0..127: u0 = Z@W + b for 2 full rows, then fused LN/softmax/LN-backward -> D, SD.
// bid 128..383: Beta = tril(Z@HZ^T,-1)+c, tile 4t x 64i.
__global__ __launch_bounds__(256) void k2(
        const float* __restrict__ Z, const float* __restrict__ W,
        const float* __restrict__ bb, const float* __restrict__ HZ,
        const float* __restrict__ c, const float* __restrict__ S,
        const float* __restrict__ gamma, const float* __restrict__ beta,
        const int* __restrict__ targets,
        float* __restrict__ u0, float* __restrict__ D, float* __restrict__ SD,
        float* __restrict__ Beta) {
    __shared__ __align__(16) float smem[8772];   // union: beta path 8768 floats, u0 path 1028
    int bid = blockIdx.x, tid = threadIdx.x;
    if (bid < 128) {
        float* At = smem;            // 2*H floats
        float* s4 = smem + 2 * H;    // 4
        int t0 = bid * 2;
        ((float4*)At)[tid] = ((const float4*)(Z + t0 * H))[tid];
        __syncthreads();
        int qc = tid;                // float2 col 0..255
        const float2* W2 = (const float2*)W;
        float a00 = 0.f, a01 = 0.f, a10 = 0.f, a11 = 0.f;
        for (int k0 = 0; k0 < H; k0 += 8) {
            float2 wv[8];
            #pragma unroll
            for (int u = 0; u < 8; ++u) wv[u] = W2[(k0 + u) * 256 + qc];
            float4 z00 = *(const float4*)&At[k0];
            float4 z01 = *(const float4*)&At[k0 + 4];
            float4 z10 = *(const float4*)&At[H + k0];
            float4 z11 = *(const float4*)&At[H + k0 + 4];
            float a0[8] = {z00.x, z00.y, z00.z, z00.w, z01.x, z01.y, z01.z, z01.w};
            float a1[8] = {z10.x, z10.y, z10.z, z10.w, z11.x, z11.y, z11.z, z11.w};
            #pragma unroll
            for (int u = 0; u < 8; ++u) {
                a00 += a0[u] * wv[u].x; a01 += a0[u] * wv[u].y;
                a10 += a1[u] * wv[u].x; a11 += a1[u] * wv[u].y;
            }
        }
        float2 bv = ((const float2*)bb)[qc];
        float2 gv = ((const float2*)gamma)[qc];
        float2 bev = ((const float2*)beta)[qc];
        float row[2][2] = {{a00 + bv.x, a01 + bv.y}, {a10 + bv.x, a11 + bv.y}};
        #pragma unroll
        for (int r = 0; r < 2; ++r) {
            int t = t0 + r;
            float v0 = row[r][0], v1 = row[r][1];
            ((float2*)u0)[t * 256 + qc] = make_float2(v0, v1);
            float m = block_sum(v0 + v1, s4) * (1.f / H);
            float d0 = v0 - m, d1 = v1 - m;
            float var = block_sum(d0 * d0 + d1 * d1, s4) * (1.f / H);
            float s = rsqrtf(var + EPSF);
            float xh0 = d0 * s, xh1 = d1 * s;
            float y0 = xh0 * gv.x + bev.x;
            float y1 = xh1 * gv.y + bev.y;
            float ymax = block_max(fmaxf(y0, y1), s4);
            float e0 = __expf(y0 - ymax), e1 = __expf(y1 - ymax);
            float Zs = block_sum(e0 + e1, s4);
            float invZ = 1.f / Zs;
            int tgt = targets[t];
            float g0 = e0 * invZ - (2 * qc == tgt ? 1.f : 0.f);
            float g1 = e1 * invZ - (2 * qc + 1 == tgt ? 1.f : 0.f);
            float gy0 = g0 * gv.x, gy1 = g1 * gv.y;
            float mgy = block_sum(gy0 + gy1, s4) * (1.f / H);
            float mgx = block_sum(gy0 * xh0 + gy1 * xh1, s4) * (1.f / H);
            float dd0 = s * (gy0 - mgy - xh0 * mgx);
            float dd1 = s * (gy1 - mgy - xh1 * mgx);
            float2 sv = ((const float2*)S)[t * 256 + qc];
            ((float2*)D)[t * 256 + qc]  = make_float2(dd0, dd1);
            ((float2*)SD)[t * 256 + qc] = make_float2(sv.x * dd0, sv.y * dd1);
        }
    } else {
        int b = bid - 128;
        int t0 = (b >> 2) * 4, i0 = (b & 3) * 64;
        int ci = tid & 63, r = tid >> 6;
        int t = t0 + r, i = i0 + ci;
        if (i0 >= t0 + 3) { Beta[t * 256 + i] = 0.f; return; }
        float* Zt = smem;            // 4*128
        float* HT = smem + 512;      // 64*129
        float acc = 0.f;
        for (int k0 = 0; k0 < H; k0 += 128) {
            __syncthreads();
            #pragma unroll
            for (int j = 0; j < 2; ++j) {
                int idx = tid + j * 256;
                Zt[(idx >> 7) * 128 + (idx & 127)] = Z[(t0 + (idx >> 7)) * H + k0 + (idx & 127)];
            }
            #pragma unroll
            for (int j = 0; j < 32; ++j) {
                int idx = tid + j * 256;
                HT[(idx >> 7) * 129 + (idx & 127)] = HZ[(i0 + (idx >> 7)) * H + k0 + (idx & 127)];
            }
            __syncthreads();
            #pragma unroll 8
            for (int k = 0; k < 128; ++k)
                acc += Zt[r * 128 + k] * HT[ci * 129 + k];
        }
        Beta[t * 256 + i] = (i < t) ? acc + c[i] : 0.f;
    }
}

// Block per row t: pre = u0 - S_t.*(Beta_t@D) + Beta_t@SD, then out = LN(pre).
__global__ __launch_bounds__(256) void k3(
        const float* __restrict__ Beta, const float* __restrict__ D,
        const float* __restrict__ SD, const float* __restrict__ u0,
        const float* __restrict__ S, const float* __restrict__ gamma,
        const float* __restrict__ beta, float* __restrict__ out) {
    __shared__ float Brow[T];
    __shared__ float s4[4];
    int t = blockIdx.x, tid = threadIdx.x;
    Brow[tid] = Beta[t * 256 + tid];
    __syncthreads();
    int qc = tid;
    const float2* D2 = (const float2*)D;
    const float2* SD2 = (const float2*)SD;
    float a1x = 0.f, a1y = 0.f, a2x = 0.f, a2y = 0.f;
    int kup = (t + 7) & ~7;
    for (int k0 = 0; k0 < kup; k0 += 8) {
        float2 dv[8], sv[8];
        #pragma unroll
        for (int u = 0; u < 8; ++u) {
            dv[u] = D2[(k0 + u) * 256 + qc];
            sv[u] = SD2[(k0 + u) * 256 + qc];
        }
        #pragma unroll
        for (int u = 0; u < 8; ++u) {
            float bw = Brow[k0 + u];
            a1x += bw * dv[u].x; a1y += bw * dv[u].y;
            a2x += bw * sv[u].x; a2y += bw * sv[u].y;
        }
    }
    float2 uv = ((const float2*)u0)[t * 256 + qc];
    float2 st = ((const float2*)S)[t * 256 + qc];
    float p0 = uv.x - st.x * a1x + a2x;
    float p1 = uv.y - st.y * a1y + a2y;
    float m = block_sum(p0 + p1, s4) * (1.f / H);
    float d0 = p0 - m, d1 = p1 - m;
    float var = block_sum(d0 * d0 + d1 * d1, s4) * (1.f / H);
    float s = rsqrtf(var + EPSF);
    float2 gv = ((const float2*)gamma)[qc];
    float2 bv = ((const float2*)beta)[qc];
    ((float2*)out)[t * 256 + qc] = make_float2(
        d0 * s * gv.x + bv.x, d1 * s * gv.y + bv.y);
}

extern "C" void kernel_launch(void* const* d_in, const int* in_sizes, int n_in,
                              void* d_out, int out_size, void* d_ws, size_t ws_size,
                              hipStream_t stream) {
    const float* h     = (const float*)d_in[0];
    const float* U     = (const float*)d_in[1];
    const float* W     = (const float*)d_in[2];
    const float* a     = (const float*)d_in[3];
    const float* b     = (const float*)d_in[4];
    const float* gamma = (const float*)d_in[5];
    const float* beta  = (const float*)d_in[6];
    const int*   tgt   = (const int*)d_in[7];
    float* out = (float*)d_out;

    float* ws = (float*)d_ws;
    float* Z    = ws;              // T*H
    float* HZ   = Z    + T * H;
    float* u0   = HZ   + T * H;
    float* D    = u0   + T * H;
    float* SD   = D    + T * H;
    float* S    = SD   + T * H;
    float* c    = S    + T * H;    // T
    float* Beta = c    + T;        // T*T

    k1<<<514, 256, 0, stream>>>(h, U, a, Z, HZ, c, S);
    k2<<<384, 256, 0, stream>>>(Z, W, b, HZ, c, S, gamma, beta, tgt, u0, D, SD, Beta);
    k3<<<T,   256, 0, stream>>>(Beta, D, SD, u0, S, gamma, beta, out);
}

// Round 6
// 114.353 us; speedup vs baseline: 1.3097x; 1.3097x over previous
//
#include <hip/hip_runtime.h>

#define T 256
#define H 512
#define EPSF 1e-5f

__device__ __forceinline__ float block_sum(float v, float* s4) {
    for (int o = 32; o; o >>= 1) v += __shfl_xor(v, o);
    int w = threadIdx.x >> 6;
    __syncthreads();
    if ((threadIdx.x & 63) == 0) s4[w] = v;
    __syncthreads();
    return s4[0] + s4[1] + s4[2] + s4[3];
}

__device__ __forceinline__ float block_max(float v, float* s4) {
    for (int o = 32; o; o >>= 1) v = fmaxf(v, __shfl_xor(v, o));
    int w = threadIdx.x >> 6;
    __syncthreads();
    if ((threadIdx.x & 63) == 0) s4[w] = v;
    __syncthreads();
    return fmaxf(fmaxf(s4[0], s4[1]), fmaxf(s4[2], s4[3]));
}

// bid 0..7: S-scan (two-pass, 64 cols/block, wave = 64-t chunk).
// bid 8..519: Z=relu(h@U+a), HZ=h.*Z, c. Tile 2t x 128q, K-split-4 across waves.
__global__ __launch_bounds__(256) void k1(
        const float* __restrict__ h, const float* __restrict__ U,
        const float* __restrict__ a, float* __restrict__ Z,
        float* __restrict__ HZ, float* __restrict__ c, float* __restrict__ S) {
    int bid = blockIdx.x, tid = threadIdx.x;
    int lane = tid & 63, w = tid >> 6;
    if (bid < 8) {
        __shared__ float csum[4][64];
        int q = bid * 64 + lane;
        int tbase = w * 64;
        float s = 0.f;
        for (int j = 0; j < 64; j += 8) {
            float v[8];
            #pragma unroll
            for (int u = 0; u < 8; ++u) v[u] = h[(tbase + j + u) * H + q];
            #pragma unroll
            for (int u = 0; u < 8; ++u) s += v[u];
        }
        csum[w][lane] = s;
        __syncthreads();
        float acc = 0.f;
        #pragma unroll
        for (int w2 = 0; w2 < 3; ++w2) if (w2 < w) acc += csum[w2][lane];
        for (int j = 0; j < 64; j += 8) {
            float v[8];
            #pragma unroll
            for (int u = 0; u < 8; ++u) v[u] = h[(tbase + j + u) * H + q];
            #pragma unroll
            for (int u = 0; u < 8; ++u) { acc += v[u]; S[(tbase + j + u) * H + q] = acc; }
        }
        return;
    }
    int b = bid - 8;
    int t0 = (b >> 2) * 2, qt = b & 3;
    __shared__ __align__(16) float sh[1024];        // 2 rows of h
    __shared__ float2 part[3][2][64];
    __shared__ float s4[4];
    (void)s4;
    ((float4*)sh)[tid] = ((const float4*)(h + t0 * H))[tid];
    __syncthreads();

    if (qt == 0 && w < 2) {                         // c[t0+w]
        float s = 0.f;
        #pragma unroll
        for (int j = 0; j < 8; ++j) s += sh[w * 512 + lane + j * 64];
        for (int o = 32; o; o >>= 1) s += __shfl_xor(s, o);
        if (lane == 0) c[t0 + w] = s;
    }

    int qc = qt * 64 + lane;                        // float2 col 0..255
    const float2* U2 = (const float2*)U;
    float2 acc0 = {0.f, 0.f}, acc1 = {0.f, 0.f};
    int kbeg = w * 128;
    for (int k0 = kbeg; k0 < kbeg + 128; k0 += 8) {
        float2 bv[8];
        #pragma unroll
        for (int u = 0; u < 8; ++u) bv[u] = U2[(k0 + u) * 256 + qc];
        float a0[8], a1[8];
        #pragma unroll
        for (int u = 0; u < 8; ++u) { a0[u] = sh[k0 + u]; a1[u] = sh[512 + k0 + u]; }
        #pragma unroll
        for (int u = 0; u < 8; ++u) {
            acc0.x += a0[u] * bv[u].x; acc0.y += a0[u] * bv[u].y;
            acc1.x += a1[u] * bv[u].x; acc1.y += a1[u] * bv[u].y;
        }
    }
    if (w) { part[w - 1][0][lane] = acc0; part[w - 1][1][lane] = acc1; }
    __syncthreads();
    if (w == 0) {
        #pragma unroll
        for (int p = 0; p < 3; ++p) {
            acc0.x += part[p][0][lane].x; acc0.y += part[p][0][lane].y;
            acc1.x += part[p][1][lane].x; acc1.y += part[p][1][lane].y;
        }
        float2 av = ((const float2*)a)[qc];
        float z0x = fmaxf(acc0.x + av.x, 0.f), z0y = fmaxf(acc0.y + av.y, 0.f);
        float z1x = fmaxf(acc1.x + av.x, 0.f), z1y = fmaxf(acc1.y + av.y, 0.f);
        float2 h0 = ((float2*)sh)[qc], h1 = ((float2*)sh)[256 + qc];
        ((float2*)Z)[t0 * 256 + qc]        = make_float2(z0x, z0y);
        ((float2*)Z)[(t0 + 1) * 256 + qc]  = make_float2(z1x, z1y);
        ((float2*)HZ)[t0 * 256 + qc]       = make_float2(h0.x * z0x, h0.y * z0y);
        ((float2*)HZ)[(t0 + 1) * 256 + qc] = make_float2(h1.x * z1x, h1.y * z1y);
    }
}

// bid 0..511: u0 = Z@W + b (tile 2t x 128q, K-split-4).
// bid 512..1535: Beta = tril(Z@HZ^T,-1)+c, 8t x 8i tiles, K-split-4 per thread.
__global__ __launch_bounds__(256) void k2(
        const float* __restrict__ Z, const float* __restrict__ W,
        const float* __restrict__ bb, const float* __restrict__ HZ,
        const float* __restrict__ c, float* __restrict__ u0,
        float* __restrict__ Beta) {
    __shared__ __align__(16) float smem[2 * 8 * 516 + 256];   // beta path; u0 path uses prefix
    int bid = blockIdx.x, tid = threadIdx.x;
    int lane = tid & 63, w = tid >> 6;
    if (bid < 512) {
        float* sh = smem;                       // 1024 floats
        float2* part = (float2*)(smem + 1024);  // 3*2*64 float2 = 3072 floats
        int t0 = (bid >> 2) * 2, qt = bid & 3;
        ((float4*)sh)[tid] = ((const float4*)(Z + t0 * H))[tid];
        __syncthreads();
        int qc = qt * 64 + lane;
        const float2* W2 = (const float2*)W;
        float2 acc0 = {0.f, 0.f}, acc1 = {0.f, 0.f};
        int kbeg = w * 128;
        for (int k0 = kbeg; k0 < kbeg + 128; k0 += 8) {
            float2 bv[8];
            #pragma unroll
            for (int u = 0; u < 8; ++u) bv[u] = W2[(k0 + u) * 256 + qc];
            float a0[8], a1[8];
            #pragma unroll
            for (int u = 0; u < 8; ++u) { a0[u] = sh[k0 + u]; a1[u] = sh[512 + k0 + u]; }
            #pragma unroll
            for (int u = 0; u < 8; ++u) {
                acc0.x += a0[u] * bv[u].x; acc0.y += a0[u] * bv[u].y;
                acc1.x += a1[u] * bv[u].x; acc1.y += a1[u] * bv[u].y;
            }
        }
        if (w) { part[((w - 1) * 2 + 0) * 64 + lane] = acc0; part[((w - 1) * 2 + 1) * 64 + lane] = acc1; }
        __syncthreads();
        if (w == 0) {
            #pragma unroll
            for (int p = 0; p < 3; ++p) {
                float2 p0 = part[(p * 2 + 0) * 64 + lane];
                float2 p1 = part[(p * 2 + 1) * 64 + lane];
                acc0.x += p0.x; acc0.y += p0.y;
                acc1.x += p1.x; acc1.y += p1.y;
            }
            float2 bv = ((const float2*)bb)[qc];
            ((float2*)u0)[t0 * 256 + qc]       = make_float2(acc0.x + bv.x, acc0.y + bv.y);
            ((float2*)u0)[(t0 + 1) * 256 + qc] = make_float2(acc1.x + bv.x, acc1.y + bv.y);
        }
    } else {
        int b = bid - 512;
        int ti = b >> 5, ii = b & 31;
        if (ii > ti) return;
        int t0 = ti * 8, i0 = ii * 8;
        float* Zs = smem;                 // [8][516]
        float* Hs = smem + 8 * 516;       // [8][516]
        float* red = smem + 2 * 8 * 516;  // [4][64]
        #pragma unroll
        for (int j = 0; j < 4; ++j) {
            int idx = tid + j * 256;      // float4 index 0..1023
            int row = idx >> 7, col4 = idx & 127;
            float4 v = ((const float4*)(Z + (t0 + row) * H))[col4];
            *(float4*)&Zs[row * 516 + col4 * 4] = v;
            float4 g = ((const float4*)(HZ + (i0 + row) * H))[col4];
            *(float4*)&Hs[row * 516 + col4 * 4] = g;
        }
        __syncthreads();
        int ks = tid >> 6, r = (tid >> 3) & 7, ci = tid & 7;
        float acc = 0.f;
        int kb = ks * 128;
        #pragma unroll 4
        for (int k0 = kb; k0 < kb + 128; k0 += 8) {
            float4 z0 = *(float4*)&Zs[r * 516 + k0];
            float4 z1 = *(float4*)&Zs[r * 516 + k0 + 4];
            float4 h0 = *(float4*)&Hs[ci * 516 + k0];
            float4 h1 = *(float4*)&Hs[ci * 516 + k0 + 4];
            acc += z0.x * h0.x + z0.y * h0.y + z0.z * h0.z + z0.w * h0.w
                 + z1.x * h1.x + z1.y * h1.y + z1.z * h1.z + z1.w * h1.w;
        }
        red[ks * 64 + r * 8 + ci] = acc;
        __syncthreads();
        if (tid < 64) {
            int r2 = tid >> 3, c2 = tid & 7;
            float v = red[tid] + red[64 + tid] + red[128 + tid] + red[192 + tid];
            int t = t0 + r2, i = i0 + c2;
            Beta[t * 256 + i] = (i < t) ? v + c[i] : 0.f;
        }
    }
}

// Per-row t: y=LN(u0), g=softmax(y)-onehot, D=LN-backward(g), SD=S.*D
__global__ __launch_bounds__(256) void k3(
        const float* __restrict__ u0, const float* __restrict__ gamma,
        const float* __restrict__ beta, const int* __restrict__ targets,
        const float* __restrict__ S, float* __restrict__ D, float* __restrict__ SD) {
    __shared__ float s4[4];
    int t = blockIdx.x, tid = threadIdx.x;
    float2 uv = ((const float2*)u0)[t * 256 + tid];
    float2 gv = ((const float2*)gamma)[tid];
    float2 bv = ((const float2*)beta)[tid];

    float m = block_sum(uv.x + uv.y, s4) * (1.f / H);
    float d0 = uv.x - m, d1 = uv.y - m;
    float var = block_sum(d0 * d0 + d1 * d1, s4) * (1.f / H);
    float s = rsqrtf(var + EPSF);
    float xh0 = d0 * s, xh1 = d1 * s;
    float y0 = xh0 * gv.x + bv.x;
    float y1 = xh1 * gv.y + bv.y;

    float ymax = block_max(fmaxf(y0, y1), s4);
    float e0 = __expf(y0 - ymax), e1 = __expf(y1 - ymax);
    float Zs = block_sum(e0 + e1, s4);
    float invZ = 1.f / Zs;
    int tgt = targets[t];
    float g0 = e0 * invZ - (2 * tid == tgt ? 1.f : 0.f);
    float g1 = e1 * invZ - (2 * tid + 1 == tgt ? 1.f : 0.f);
    float gy0 = g0 * gv.x, gy1 = g1 * gv.y;

    float mgy = block_sum(gy0 + gy1, s4) * (1.f / H);
    float mgx = block_sum(gy0 * xh0 + gy1 * xh1, s4) * (1.f / H);

    float dd0 = s * (gy0 - mgy - xh0 * mgx);
    float dd1 = s * (gy1 - mgy - xh1 * mgx);
    float2 sv = ((const float2*)S)[t * 256 + tid];
    ((float2*)D)[t * 256 + tid]  = make_float2(dd0, dd1);
    ((float2*)SD)[t * 256 + tid] = make_float2(sv.x * dd0, sv.y * dd1);
}

// bid = t*2 + khalf: partial A1 = Beta_t@D, A2 = Beta_t@SD over i-half.
__global__ __launch_bounds__(256) void k5(
        const float* __restrict__ Beta, const float* __restrict__ D,
        const float* __restrict__ SD, float* __restrict__ A1p,
        float* __restrict__ A2p) {
    int bid = blockIdx.x, tid = threadIdx.x;
    int t = bid >> 1, kh = bid & 1;
    int qc = tid;
    int ibeg = kh * 128;
    int kup;
    if (kh == 0) kup = (t >= 128) ? 128 : ((t + 7) & ~7);
    else         kup = (t > 128) ? ((t + 7) & ~7) : 128;
    const float2* D2 = (const float2*)D;
    const float2* SD2 = (const float2*)SD;
    float2 a1 = {0.f, 0.f}, a2 = {0.f, 0.f};
    for (int k0 = ibeg; k0 < kup; k0 += 8) {
        float2 dv[8], sv[8];
        #pragma unroll
        for (int u = 0; u < 8; ++u) {
            dv[u] = D2[(k0 + u) * 256 + qc];
            sv[u] = SD2[(k0 + u) * 256 + qc];
        }
        #pragma unroll
        for (int u = 0; u < 8; ++u) {
            float bw = Beta[t * 256 + k0 + u];
            a1.x += bw * dv[u].x; a1.y += bw * dv[u].y;
            a2.x += bw * sv[u].x; a2.y += bw * sv[u].y;
        }
    }
    ((float2*)A1p)[(kh * T + t) * 256 + qc] = a1;
    ((float2*)A2p)[(kh * T + t) * 256 + qc] = a2;
}

// pre = u0 - S_t.*(A1a+A1b) + (A2a+A2b); out = LN(pre)
__global__ __launch_bounds__(256) void k6(
        const float* __restrict__ A1p, const float* __restrict__ A2p,
        const float* __restrict__ u0, const float* __restrict__ S,
        const float* __restrict__ gamma, const float* __restrict__ beta,
        float* __restrict__ out) {
    __shared__ float s4[4];
    int t = blockIdx.x, tid = threadIdx.x, qc = tid;
    float2 a1a = ((const float2*)A1p)[t * 256 + qc];
    float2 a1b = ((const float2*)A1p)[(T + t) * 256 + qc];
    float2 a2a = ((const float2*)A2p)[t * 256 + qc];
    float2 a2b = ((const float2*)A2p)[(T + t) * 256 + qc];
    float2 uv = ((const float2*)u0)[t * 256 + qc];
    float2 st = ((const float2*)S)[t * 256 + qc];
    float p0 = uv.x - st.x * (a1a.x + a1b.x) + (a2a.x + a2b.x);
    float p1 = uv.y - st.y * (a1a.y + a1b.y) + (a2a.y + a2b.y);
    float m = block_sum(p0 + p1, s4) * (1.f / H);
    float d0 = p0 - m, d1 = p1 - m;
    float var = block_sum(d0 * d0 + d1 * d1, s4) * (1.f / H);
    float s = rsqrtf(var + EPSF);
    float2 gv = ((const float2*)gamma)[qc];
    float2 bv = ((const float2*)beta)[qc];
    ((float2*)out)[t * 256 + qc] = make_float2(
        d0 * s * gv.x + bv.x, d1 * s * gv.y + bv.y);
}

extern "C" void kernel_launch(void* const* d_in, const int* in_sizes, int n_in,
                              void* d_out, int out_size, void* d_ws, size_t ws_size,
                              hipStream_t stream) {
    const float* h     = (const float*)d_in[0];
    const float* U     = (const float*)d_in[1];
    const float* W     = (const float*)d_in[2];
    const float* a     = (const float*)d_in[3];
    const float* b     = (const float*)d_in[4];
    const float* gamma = (const float*)d_in[5];
    const float* beta  = (const float*)d_in[6];
    const int*   tgt   = (const int*)d_in[7];
    float* out = (float*)d_out;

    float* ws = (float*)d_ws;
    float* Z    = ws;               // T*H
    float* HZ   = Z    + T * H;
    float* u0   = HZ   + T * H;
    float* D    = u0   + T * H;
    float* SD   = D    + T * H;
    float* S    = SD   + T * H;
    float* A1p  = S    + T * H;     // 2*T*H
    float* A2p  = A1p  + 2 * T * H; // 2*T*H
    float* c    = A2p  + 2 * T * H; // T
    float* Beta = c    + T;         // T*T

    k1<<<520,  256, 0, stream>>>(h, U, a, Z, HZ, c, S);
    k2<<<1536, 256, 0, stream>>>(Z, W, b, HZ, c, u0, Beta);
    k3<<<T,    256, 0, stream>>>(u0, gamma, beta, tgt, S, D, SD);
    k5<<<2 * T, 256, 0, stream>>>(Beta, D, SD, A1p, A2p);
    k6<<<T,    256, 0, stream>>>(A1p, A2p, u0, S, gamma, beta, out);
}